// Round 12
// baseline (868.433 us; speedup 1.0000x reference)
//
#include <hip/hip_runtime.h>
#include <math.h>

#define CDIM  128
#define NHEAD 8
#define DHEAD 16
#define NPAT  50000
#define NICD  591
#define NNDC  2042
#define OUTN  90
#define NEDGE 250000
#define NLAYER 2
#define EPB   64

// concat offsets for CSR build (relation order: pi, ip, pn, np; dst sizes)
#define OFF0  0
#define OFF1  (NICD)
#define OFF2  (NICD + NPAT)
#define OFF3  (NICD + NPAT + NNDC)
#define NTOT  (NICD + NPAT + NNDC + NPAT)

#define LDP 40   // GEMM LDS row stride (bf16 elems)

typedef __attribute__((ext_vector_type(8))) short bf16x8;
typedef __attribute__((ext_vector_type(4))) float f32x4;

__device__ __forceinline__ float gelu_tanh(float x) {
    float x3 = x * x * x;
    return 0.5f * x * (1.0f + tanhf(0.7978845608028654f * (x + 0.044715f * x3)));
}
__device__ __forceinline__ float b2f(unsigned short u) {
    union { unsigned int i; float f; } v; v.i = ((unsigned int)u) << 16; return v.f;
}
__device__ __forceinline__ unsigned short f2b(float f) {
    union { float ff; unsigned int i; } v; v.ff = f;
    unsigned int i = v.i;
    return (unsigned short)((i + 0x7FFFu + ((i >> 16) & 1u)) >> 16);  // RNE
}
__device__ __forceinline__ float2 b2x2(unsigned int u) {
    union { unsigned int i; float f; } lo, hi;
    lo.i = u << 16; hi.i = u & 0xFFFF0000u;
    return make_float2(lo.f, hi.f);
}

// ---------------------------------------------------------------------------
// bf16 MFMA GEMM: D = act(A @ Wt^T + bias), Wt [N][128] bf16.
// ---------------------------------------------------------------------------
__global__ __launch_bounds__(256) void gemm_mfma(
    const void* __restrict__ Ap, int a_mode, int lda,
    const unsigned short* __restrict__ Wt, const float* __restrict__ bias,
    void* __restrict__ Cp, int c_mode, int ldc,
    int M, int N, int act,
    const unsigned short* __restrict__ xold, int ldx,
    const float* __restrict__ skipv, int skipidx)
{
    __shared__ unsigned short Al[64 * LDP];
    __shared__ unsigned short Bl[64 * LDP];
    int bm = blockIdx.x * 64, bn = blockIdx.y * 64;
    int t = threadIdx.x;
    int lane = t & 63, w = t >> 6;
    int wr = w >> 1, wc = w & 1;
    int quad = lane >> 4, lm = lane & 15;
    f32x4 acc[2][2] = {};
    const int srow = t >> 2;
    const int skq  = (t & 3) * 8;

    for (int k0 = 0; k0 < 128; k0 += 32) {
        {
            int row = bm + srow;
            uint4 u = make_uint4(0, 0, 0, 0);
            if (a_mode == 0) {
                if (row < M)
                    u = *(const uint4*)((const unsigned short*)Ap + (size_t)row * lda + k0 + skq);
            } else {
                float f[8] = {0.f,0.f,0.f,0.f,0.f,0.f,0.f,0.f};
                if (row < M) {
                    const float4* ap = (const float4*)((const float*)Ap + (size_t)row * lda + k0 + skq);
                    float4 u0 = ap[0], u1 = ap[1];
                    f[0]=u0.x; f[1]=u0.y; f[2]=u0.z; f[3]=u0.w;
                    f[4]=u1.x; f[5]=u1.y; f[6]=u1.z; f[7]=u1.w;
                    if (a_mode == 2)
                        for (int i = 0; i < 8; i++) f[i] = gelu_tanh(f[i]);
                }
                unsigned short v[8];
                for (int i = 0; i < 8; i++) v[i] = f2b(f[i]);
                u = *(uint4*)v;
            }
            *(uint4*)&Al[srow * LDP + skq] = u;
        }
        {
            int n = bn + srow;
            uint4 u = make_uint4(0, 0, 0, 0);
            if (n < N) u = *(const uint4*)(Wt + (size_t)n * 128 + k0 + skq);
            *(uint4*)&Bl[srow * LDP + skq] = u;
        }
        __syncthreads();
        bf16x8 af[2], bfr[2];
        #pragma unroll
        for (int i = 0; i < 2; i++) {
            af[i]  = *(const bf16x8*)&Al[(wr * 32 + i * 16 + lm) * LDP + quad * 8];
            bfr[i] = *(const bf16x8*)&Bl[(wc * 32 + i * 16 + lm) * LDP + quad * 8];
        }
        acc[0][0] = __builtin_amdgcn_mfma_f32_16x16x32_bf16(af[0], bfr[0], acc[0][0], 0, 0, 0);
        acc[0][1] = __builtin_amdgcn_mfma_f32_16x16x32_bf16(af[0], bfr[1], acc[0][1], 0, 0, 0);
        acc[1][0] = __builtin_amdgcn_mfma_f32_16x16x32_bf16(af[1], bfr[0], acc[1][0], 0, 0, 0);
        acc[1][1] = __builtin_amdgcn_mfma_f32_16x16x32_bf16(af[1], bfr[1], acc[1][1], 0, 0, 0);
        __syncthreads();
    }

    float aSk = 0.f, oneM = 0.f;
    if (skipv) {
        float sv = skipv[skipidx];
        aSk = 1.0f / (1.0f + expf(-sv));
        oneM = 1.0f - aSk;
    }
    #pragma unroll
    for (int tm = 0; tm < 2; tm++)
    #pragma unroll
    for (int tn = 0; tn < 2; tn++)
    #pragma unroll
    for (int r = 0; r < 4; r++) {
        int row = bm + wr * 32 + tm * 16 + quad * 4 + r;
        int col = bn + wc * 32 + tn * 16 + lm;
        if (row >= M || col >= N) continue;
        float v = acc[tm][tn][r] + (bias ? bias[col] : 0.f);
        if (act == 1) v = fmaxf(v, 0.f);
        else if (act == 2) v = 1.0f / (1.0f + expf(-v));
        if (skipv) v = aSk * v + oneM * b2f(xold[(size_t)row * ldx + col]);
        if (c_mode == 0) ((unsigned short*)Cp)[(size_t)row * ldc + col] = f2b(v);
        else             ((float*)Cp)[(size_t)row * ldc + col] = v;
    }
}

// ---------------------------------------------------------------------------
// Weight prep: transpose+convert fp32 [g][K][N] -> bf16 [n+nofs][128]
// ---------------------------------------------------------------------------
__global__ __launch_bounds__(256) void wprep_kernel(
    const float* __restrict__ src, unsigned short* __restrict__ dst,
    int K, int N, size_t sstride, size_t gstride, int nofs)
{
    __shared__ float tile[32][33];
    int g = blockIdx.z;
    int k0 = blockIdx.x * 32, n0 = blockIdx.y * 32;
    int tx = threadIdx.x & 31, ty = threadIdx.x >> 5;
    const float* s = src + (size_t)g * sstride;
    for (int i = 0; i < 32; i += 8) {
        int k = k0 + ty + i, n = n0 + tx;
        tile[ty + i][tx] = (k < K && n < N) ? s[(size_t)k * N + n] : 0.f;
    }
    __syncthreads();
    unsigned short* d = dst + (size_t)g * gstride;
    for (int i = 0; i < 32; i += 8) {
        int n = n0 + ty + i, k = k0 + tx;
        if (n < N && k < K) d[(size_t)(n + nofs) * 128 + k] = f2b(tile[tx][ty + i]);
    }
}

// ---------------------------------------------------------------------------
// Composed relation weights (as round 10)
// ---------------------------------------------------------------------------
__global__ __launch_bounds__(256) void wcomp_kernel(
    const float* __restrict__ kw, const float* __restrict__ vw,
    const float* __restrict__ a_rel, const float* __restrict__ m_rel,
    const float* __restrict__ kb, const float* __restrict__ vb,
    unsigned short* __restrict__ Wb0, unsigned short* __restrict__ Wb1,
    unsigned short* __restrict__ Wb2,
    float* __restrict__ bb0, float* __restrict__ bb1, float* __restrict__ bb2)
{
    int s = blockIdx.x;
    int l = s >> 3, j = s & 7;
    int t, isV, r, rowoff, nw;
    unsigned short* Wb; float* bb;
    switch (j) {
      case 0: t=0; isV=0; r=0; Wb=Wb0; bb=bb0; rowoff=128; nw=640; break;
      case 1: t=0; isV=1; r=0; Wb=Wb0; bb=bb0; rowoff=256; nw=640; break;
      case 2: t=0; isV=0; r=2; Wb=Wb0; bb=bb0; rowoff=384; nw=640; break;
      case 3: t=0; isV=1; r=2; Wb=Wb0; bb=bb0; rowoff=512; nw=640; break;
      case 4: t=1; isV=0; r=1; Wb=Wb1; bb=bb1; rowoff=128; nw=384; break;
      case 5: t=1; isV=1; r=1; Wb=Wb1; bb=bb1; rowoff=256; nw=384; break;
      case 6: t=2; isV=0; r=3; Wb=Wb2; bb=bb2; rowoff=128; nw=384; break;
      default:t=2; isV=1; r=3; Wb=Wb2; bb=bb2; rowoff=256; nw=384; break;
    }
    const float* W = (isV ? vw : kw) + (size_t)(l * 3 + t) * 16384;
    const float* A = (isV ? m_rel : a_rel) + (size_t)(l * 4 + r) * 2048;
    const float* B = (isV ? vb : kb) + (size_t)(l * 3 + t) * 128;
    unsigned short* dst = Wb + (size_t)l * nw * 128 + (size_t)rowoff * 128;
    float* bdst = bb + (size_t)l * nw + rowoff;
    int n = threadIdx.x & 127;
    int kh = threadIdx.x >> 7;
    int h = n >> 4, e = n & 15;
    float Ar[16];
    #pragma unroll
    for (int d = 0; d < 16; d++) Ar[d] = A[h * 256 + d * 16 + e];
    for (int k = kh * 64; k < kh * 64 + 64; k++) {
        float acc = 0.f;
        const float* wr = W + (size_t)k * 128 + h * 16;
        #pragma unroll
        for (int d = 0; d < 16; d++) acc += wr[d] * Ar[d];
        dst[(size_t)n * 128 + k] = f2b(acc);
    }
    if (kh == 0) {
        float acc = 0.f;
        const float* br = B + h * 16;
        #pragma unroll
        for (int d = 0; d < 16; d++) acc += br[d] * Ar[d];
        bdst[n] = acc;
    }
}

__global__ void biasq_kernel(const float* __restrict__ qb,
                             float* __restrict__ bb0, float* __restrict__ bb1,
                             float* __restrict__ bb2) {
    int t = blockIdx.x * blockDim.x + threadIdx.x;
    if (t >= 6 * 128) return;
    int g = t >> 7, c = t & 127;
    int l = g / 3, ty = g % 3;
    float v = qb[g * 128 + c];
    if (ty == 0) bb0[l * 640 + c] = v;
    else if (ty == 1) bb1[l * 384 + c] = v;
    else bb2[l * 384 + c] = v;
}

// ---------------------------------------------------------------------------
// Histogram: grid (64, 4). icd/ndc relations pre-aggregate in LDS.
// ---------------------------------------------------------------------------
__global__ __launch_bounds__(256) void hist4_kernel(
    const int* __restrict__ d0, const int* __restrict__ d1,
    const int* __restrict__ d2, const int* __restrict__ d3,
    int* __restrict__ deg)
{
    __shared__ int lh[2048];
    int rel = blockIdx.y;
    int t = threadIdx.x;
    const int* dp = (rel == 0) ? d0 : (rel == 1) ? d1 : (rel == 2) ? d2 : d3;
    int off = (rel == 0) ? OFF0 : (rel == 1) ? OFF1 : (rel == 2) ? OFF2 : OFF3;
    if (rel == 1 || rel == 3) {
        for (int e = blockIdx.x * 256 + t; e < NEDGE; e += gridDim.x * 256)
            atomicAdd(&deg[off + dp[e]], 1);
    } else {
        int nb = (rel == 0) ? NICD : NNDC;
        for (int i = t; i < nb; i += 256) lh[i] = 0;
        __syncthreads();
        for (int e = blockIdx.x * 256 + t; e < NEDGE; e += gridDim.x * 256)
            atomicAdd(&lh[dp[e]], 1);
        __syncthreads();
        for (int i = t; i < nb; i += 256) {
            int v = lh[i];
            if (v) atomicAdd(&deg[off + i], v);
        }
    }
}

__global__ __launch_bounds__(256) void scanA_kernel(
    const int* __restrict__ deg, int* __restrict__ part, int n)
{
    __shared__ int red[256];
    int b = blockIdx.x, t = threadIdx.x;
    int base = b * 1024 + t * 4;
    int s = 0;
    if (base + 3 < n) {
        int4 v = *(const int4*)(deg + base);
        s = v.x + v.y + v.z + v.w;
    } else {
        for (int i = 0; i < 4; i++) if (base + i < n) s += deg[base + i];
    }
    red[t] = s;
    __syncthreads();
    for (int o = 128; o; o >>= 1) { if (t < o) red[t] += red[t + o]; __syncthreads(); }
    if (t == 0) part[b] = red[0];
}

__global__ __launch_bounds__(128) void scanB_kernel(int* __restrict__ part, int nb)
{
    __shared__ int s[256];
    int t = threadIdx.x;
    for (int i = t; i < nb; i += 128) s[i] = part[i];
    __syncthreads();
    if (t == 0) { int run = 0; for (int i = 0; i < nb; i++) { int v = s[i]; s[i] = run; run += v; } }
    __syncthreads();
    for (int i = t; i < nb; i += 128) part[i] = s[i];
}

__global__ __launch_bounds__(256) void scanC_kernel(
    const int* __restrict__ deg, const int* __restrict__ part,
    int* __restrict__ rp0, int* __restrict__ rp1,
    int* __restrict__ rp2, int* __restrict__ rp3,
    int* __restrict__ cursor, int n)
{
    __shared__ int red[256];
    int b = blockIdx.x, t = threadIdx.x;
    int base = b * 1024 + t * 4;
    int v[4] = {0, 0, 0, 0};
    if (base + 3 < n) {
        int4 q = *(const int4*)(deg + base);
        v[0] = q.x; v[1] = q.y; v[2] = q.z; v[3] = q.w;
    } else {
        for (int i = 0; i < 4; i++) if (base + i < n) v[i] = deg[base + i];
    }
    red[t] = v[0] + v[1] + v[2] + v[3];
    __syncthreads();
    for (int off = 1; off < 256; off <<= 1) {
        int y = (t >= off) ? red[t - off] : 0;
        __syncthreads();
        red[t] += y;
        __syncthreads();
    }
    int run = part[b] + ((t == 0) ? 0 : red[t - 1]);
    for (int i = 0; i < 4; i++) {
        int g = base + i;
        if (g < n) {
            cursor[g] = run;
            int r, loc;
            if      (g < OFF1) { r = 0; loc = g; }
            else if (g < OFF2) { r = 1; loc = g - OFF1; }
            else if (g < OFF3) { r = 2; loc = g - OFF2; }
            else               { r = 3; loc = g - OFF3; }
            int Sl = run - r * NEDGE;
            ((r == 0) ? rp0 : (r == 1) ? rp1 : (r == 2) ? rp2 : rp3)[loc] = Sl;
            run += v[i];
        }
    }
    if (b == 0 && t == 0) {
        rp0[NICD] = NEDGE; rp1[NPAT] = NEDGE; rp2[NNDC] = NEDGE; rp3[NPAT] = NEDGE;
    }
}

// ---------------------------------------------------------------------------
// Scatter, grid (64, 4). Patient relations: plain. icd/ndc: LDS reservation.
// ---------------------------------------------------------------------------
__global__ __launch_bounds__(256) void scatter_pack_kernel(
    const int* __restrict__ s0, const int* __restrict__ d0,
    const int* __restrict__ s1, const int* __restrict__ d1,
    const int* __restrict__ s2, const int* __restrict__ d2,
    const int* __restrict__ s3, const int* __restrict__ d3,
    int* __restrict__ cursor, unsigned int* __restrict__ es)
{
    __shared__ int lcnt[2048];
    __shared__ int lbase[2048];
    int rel = blockIdx.y;
    int t = threadIdx.x;
    const int* sp = (rel == 0) ? s0 : (rel == 1) ? s1 : (rel == 2) ? s2 : s3;
    const int* dp = (rel == 0) ? d0 : (rel == 1) ? d1 : (rel == 2) ? d2 : d3;
    int off = (rel == 0) ? OFF0 : (rel == 1) ? OFF1 : (rel == 2) ? OFF2 : OFF3;
    if (rel == 1 || rel == 3) {
        for (int e = blockIdx.x * 256 + t; e < NEDGE; e += gridDim.x * 256) {
            int d = dp[e];
            int p = atomicAdd(&cursor[off + d], 1);
            es[p] = ((unsigned int)sp[e] << 16) | (unsigned int)d;
        }
    } else {
        int nb = (rel == 0) ? NICD : NNDC;
        int per = (NEDGE + gridDim.x - 1) / gridDim.x;
        int e0 = blockIdx.x * per, e1 = min(e0 + per, NEDGE);
        for (int i = t; i < nb; i += 256) lcnt[i] = 0;
        __syncthreads();
        for (int e = e0 + t; e < e1; e += 256) atomicAdd(&lcnt[dp[e]], 1);
        __syncthreads();
        for (int i = t; i < nb; i += 256) {
            int c = lcnt[i];
            lbase[i] = c ? atomicAdd(&cursor[off + i], c) : 0;
            lcnt[i] = 0;
        }
        __syncthreads();
        for (int e = e0 + t; e < e1; e += 256) {
            int d = dp[e];
            int p = lbase[d] + atomicAdd(&lcnt[d], 1);
            es[p] = ((unsigned int)sp[e] << 16) | (unsigned int)d;
        }
    }
}

// ---------------------------------------------------------------------------
// x = relu(emb[idx]) gather -> bf16
// ---------------------------------------------------------------------------
__global__ void gather_relu_kernel(const float* __restrict__ emb,
                                   const int* __restrict__ idx,
                                   unsigned short* __restrict__ out, int n) {
    int t = blockIdx.x * blockDim.x + threadIdx.x;
    if (t < n * CDIM) {
        int r = t >> 7, c = t & 127;
        out[t] = f2b(fmaxf(emb[(size_t)idx[r] * CDIM + c], 0.f));
    }
}

__device__ __forceinline__ float dot16_bf(const unsigned short* a,
                                          const unsigned short* b) {
    const uint4* ap = (const uint4*)a;
    const uint4* bp = (const uint4*)b;
    uint4 a0 = ap[0], a1 = ap[1], b0 = bp[0], b1 = bp[1];
    unsigned int au[8] = {a0.x, a0.y, a0.z, a0.w, a1.x, a1.y, a1.z, a1.w};
    unsigned int bu[8] = {b0.x, b0.y, b0.z, b0.w, b1.x, b1.y, b1.z, b1.w};
    float acc = 0.f;
    #pragma unroll
    for (int j = 0; j < 8; j++) {
        float2 x = b2x2(au[j]), y = b2x2(bu[j]);
        acc += x.x * y.x + x.y * y.y;
    }
    return acc;
}

// ---------------------------------------------------------------------------
// Per-edge logits (icd/ndc-dst path); kr lives inside the wide P0 buffer.
// ---------------------------------------------------------------------------
__global__ __launch_bounds__(256) void edge_logits_kernel(
    const unsigned int* __restrict__ es,
    const unsigned short* __restrict__ q, int ldq,
    const unsigned short* __restrict__ kr, int ldk,
    const float* __restrict__ prel, float* __restrict__ alpha_s)
{
    int t = blockIdx.x * blockDim.x + threadIdx.x;
    if (t >= NEDGE * NHEAD) return;
    int i = t >> 3, h = t & 7;
    unsigned int ed = es[i];
    int dn = ed & 0xFFFFu, sn = ed >> 16;
    float acc = dot16_bf(q + (size_t)dn * ldq + h * DHEAD,
                         kr + (size_t)sn * ldk + h * DHEAD);
    alpha_s[t] = acc * prel[h] * 0.25f;
}

__global__ __launch_bounds__(256) void seg_stats_kernel(
    const int* __restrict__ rowptr, const float* __restrict__ alpha_s,
    float2* __restrict__ stats, int nd)
{
    int wid = (blockIdx.x * 256 + threadIdx.x) >> 6;
    int lane = threadIdx.x & 63;
    if (wid >= nd) return;
    int r0 = rowptr[wid], r1 = rowptr[wid + 1];
    int h = lane & 7, j = lane >> 3;
    float mx = -1e30f;
    for (int i = r0 + j; i < r1; i += 8)
        mx = fmaxf(mx, alpha_s[(size_t)i * NHEAD + h]);
    mx = fmaxf(mx, __shfl_xor(mx, 8));
    mx = fmaxf(mx, __shfl_xor(mx, 16));
    mx = fmaxf(mx, __shfl_xor(mx, 32));
    float sm = 0.f;
    for (int i = r0 + j; i < r1; i += 8)
        sm += expf(alpha_s[(size_t)i * NHEAD + h] - mx);
    sm += __shfl_xor(sm, 8);
    sm += __shfl_xor(sm, 16);
    sm += __shfl_xor(sm, 32);
    if (j == 0)
        stats[(size_t)wid * NHEAD + h] = make_float2(mx, (sm > 0.f) ? 1.0f / sm : 0.f);
}

// ---------------------------------------------------------------------------
// Patient-dst path, PAIRED-WAVE version: block = 4 waves = 2 patients x 2
// relations. Each wave computes one relation's logits+softmax+partial agg;
// the pair combines through LDS and the rel-1 wave does the single PURE
// STORE of agg[0] (sole owner -> no memset, no RMW). Halves the per-wave
// serial chain vs the round-10 fused kernel; doubles wave count.
// ---------------------------------------------------------------------------
__global__ __launch_bounds__(256) void edge_softmax_agg2_kernel(
    const int* __restrict__ rp1, const unsigned int* __restrict__ es1,
    const int* __restrict__ rp3, const unsigned int* __restrict__ es3,
    const unsigned short* __restrict__ q, int ldq,
    const unsigned short* __restrict__ kr1, const unsigned short* __restrict__ vr1, int ld1,
    const unsigned short* __restrict__ kr3, const unsigned short* __restrict__ vr3, int ld3,
    const float* __restrict__ prel1, const float* __restrict__ prel3,
    float* __restrict__ agg, int nd)
{
    __shared__ float wls[4][64 * NHEAD];   // 8 KB logit scratch per wave
    __shared__ float cmb[2][CDIM];         // 1 KB combine buffer per patient slot
    int wv   = threadIdx.x >> 6;
    int lane = threadIdx.x & 63;
    int pl = wv >> 1;                       // patient slot in block (0..1)
    int rr = wv & 1;                        // relation (0 -> icd->pat, 1 -> ndc->pat)
    int wid = blockIdx.x * 2 + pl;
    bool valid = (wid < nd);
    float acc0 = 0.f, acc1 = 0.f;

    if (valid) {
        const int* rp = rr ? rp3 : rp1;
        const unsigned int* es = rr ? es3 : es1;
        const unsigned short* kr = rr ? kr3 : kr1;
        const unsigned short* vr = rr ? vr3 : vr1;
        int ld = rr ? ld3 : ld1;
        const float* prel = rr ? prel3 : prel1;
        int r0 = rp[wid], r1v = rp[wid + 1];
        int deg = r1v - r0;
        if (deg > 0) {
            float* wl = wls[wv];
            int h = lane & 7, j = lane >> 3;
            int hc = lane >> 3;
            const unsigned short* qbase = q + (size_t)wid * ldq;
            const unsigned short* qrow = qbase + h * DHEAD;
            float ph = prel[h] * 0.25f;
            bool small = (deg <= 64);

            float m = -1e30f;
            for (int i = j; i < deg; i += 8) {
                int sn = es[r0 + i] >> 16;
                float a = dot16_bf(qrow, kr + (size_t)sn * ld + h * DHEAD) * ph;
                if (small) wl[i * NHEAD + h] = a;
                m = fmaxf(m, a);
            }
            m = fmaxf(m, __shfl_xor(m, 8));
            m = fmaxf(m, __shfl_xor(m, 16));
            m = fmaxf(m, __shfl_xor(m, 32));
            float s = 0.f;
            for (int i = j; i < deg; i += 8) {
                float a;
                if (small) a = wl[i * NHEAD + h];
                else {
                    int sn = es[r0 + i] >> 16;
                    a = dot16_bf(qrow, kr + (size_t)sn * ld + h * DHEAD) * ph;
                }
                float e = expf(a - m);
                if (small) wl[i * NHEAD + h] = e;
                s += e;
            }
            s += __shfl_xor(s, 8);
            s += __shfl_xor(s, 16);
            s += __shfl_xor(s, 32);
            float si = (s > 0.f) ? 1.0f / s : 0.f;
            if (small)
                for (int i = j; i < deg; i += 8)
                    wl[i * NHEAD + h] *= si;

            float m_hc  = __shfl(m, hc);
            float si_hc = __shfl(si, hc);
            float ph_hc = __shfl(ph, hc);
            const unsigned short* qrow_hc = qbase + hc * DHEAD;
            for (int i = 0; i < deg; i++) {
                unsigned int sv = es[r0 + i] >> 16;
                unsigned int pv = *(const unsigned int*)(vr + (size_t)sv * ld + 2 * lane);
                float2 v = b2x2(pv);
                float wgt;
                if (small) wgt = wl[i * NHEAD + hc];
                else {
                    float a = dot16_bf(qrow_hc, kr + (size_t)sv * ld + hc * DHEAD) * ph_hc;
                    wgt = expf(a - m_hc) * si_hc;
                }
                acc0 += wgt * v.x;
                acc1 += wgt * v.y;
            }
        }
    }

    // pair combine: rel-0 wave parks partials, rel-1 wave adds + stores
    if (rr == 0) {
        cmb[pl][2 * lane]     = acc0;
        cmb[pl][2 * lane + 1] = acc1;
    }
    __syncthreads();
    if (rr == 1 && valid) {
        float2* ap = (float2*)(agg + (size_t)wid * CDIM + 2 * lane);
        *ap = make_float2(cmb[pl][2 * lane] + acc0, cmb[pl][2 * lane + 1] + acc1);
    }
}

// ---------------------------------------------------------------------------
// Edge-chunk weighted segment sum — stats variant (icd/ndc-dst path)
// ---------------------------------------------------------------------------
__global__ __launch_bounds__(128) void seg_agg_kernel(
    const unsigned int* __restrict__ es,
    const float* __restrict__ alpha_s, const float2* __restrict__ stats,
    const unsigned short* __restrict__ vr, int ldv,
    float* __restrict__ agg, int ne)
{
    __shared__ unsigned int sE[EPB];
    __shared__ float sW[EPB][NHEAD + 1];
    int i0 = blockIdx.x * EPB;
    int t  = threadIdx.x;
    int cnt = min(EPB, ne - i0);
    if (t < cnt) {
        unsigned int ed = es[i0 + t];
        sE[t] = ed;
        int dn = ed & 0xFFFFu;
        const float4* ap = (const float4*)(alpha_s + (size_t)(i0 + t) * NHEAD);
        float4 a0 = ap[0], a1 = ap[1];
        float wv[8] = {a0.x, a0.y, a0.z, a0.w, a1.x, a1.y, a1.z, a1.w};
        const float2* st = stats + (size_t)dn * NHEAD;
        #pragma unroll
        for (int h = 0; h < NHEAD; h++) {
            float2 ms = st[h];
            sW[t][h] = expf(wv[h] - ms.x) * ms.y;
        }
    }
    __syncthreads();
    int h = t >> 4;
    float acc = 0.f;
    int curd = (int)(sE[0] & 0xFFFFu);
    for (int i = 0; i < cnt; i++) {
        unsigned int ed = sE[i];
        int d = (int)(ed & 0xFFFFu);
        if (d != curd) {
            atomicAdd(&agg[(size_t)curd * CDIM + t], acc);
            acc = 0.f;
            curd = d;
        }
        acc += b2f(vr[(size_t)(ed >> 16) * ldv + t]) * sW[i][h];
    }
    atomicAdd(&agg[(size_t)curd * CDIM + t], acc);
}

// ---------------------------------------------------------------------------
extern "C" void kernel_launch(void* const* d_in, const int* in_sizes, int n_in,
                              void* d_out, int out_size, void* d_ws, size_t ws_size,
                              hipStream_t stream)
{
    const float* x_patient = (const float*)d_in[0];
    const float* w_in      = (const float*)d_in[1];
    const float* b_in      = (const float*)d_in[2];
    const float* emb_icd   = (const float*)d_in[3];
    const float* emb_ndc   = (const float*)d_in[4];
    const float* kw        = (const float*)d_in[5];
    const float* kbias     = (const float*)d_in[6];
    const float* qw        = (const float*)d_in[7];
    const float* qbias     = (const float*)d_in[8];
    const float* vw        = (const float*)d_in[9];
    const float* vbias     = (const float*)d_in[10];
    const float* aw        = (const float*)d_in[11];
    const float* abias     = (const float*)d_in[12];
    const float* skip      = (const float*)d_in[13];
    const float* a_rel     = (const float*)d_in[14];
    const float* m_rel     = (const float*)d_in[15];
    const float* p_rel     = (const float*)d_in[16];
    const float* w_out     = (const float*)d_in[17];
    const float* b_out     = (const float*)d_in[18];
    const int*   x_icd     = (const int*)d_in[19];
    const int*   x_ndc     = (const int*)d_in[20];
    const int* esrc[4] = {(const int*)d_in[21], (const int*)d_in[23],
                          (const int*)d_in[25], (const int*)d_in[27]};
    const int* edst[4] = {(const int*)d_in[22], (const int*)d_in[24],
                          (const int*)d_in[26], (const int*)d_in[28]};

    const int sizes[3] = {NPAT, NICD, NNDC};

    char* p = (char*)d_ws;
    auto alloc = [&](size_t bytes) -> void* {
        void* r = (void*)p;
        p += (bytes + 255) & ~(size_t)255;
        return r;
    };

    unsigned short *xb[3];
    for (int t = 0; t < 3; t++) xb[t] = (unsigned short*)alloc((size_t)sizes[t] * CDIM * 2);
    // wide projection buffers: P0 [NPAT][640] = q|kr0|vr0|kr2|vr2; P1/P2 [n][384] = q|kr|vr
    unsigned short* P0 = (unsigned short*)alloc((size_t)NPAT * 640 * 2);
    unsigned short* P1 = (unsigned short*)alloc((size_t)NICD * 384 * 2);
    unsigned short* P2 = (unsigned short*)alloc((size_t)NNDC * 384 * 2);
    float* aggbase = (float*)alloc((size_t)(NPAT + NICD + NNDC) * CDIM * 4);
    float* agg[3];
    agg[0] = aggbase;
    agg[1] = aggbase + (size_t)NPAT * CDIM;
    agg[2] = agg[1] + (size_t)NICD * CDIM;
    float*  alphabuf = (float*)alloc((size_t)NEDGE * NHEAD * 4);
    float2* statsbuf = (float2*)alloc((size_t)NNDC * NHEAD * 8);
    unsigned int* esbig = (unsigned int*)alloc((size_t)4 * NEDGE * 4);
    int* rowptr[4];
    rowptr[0] = (int*)alloc((size_t)(NICD + 1) * 4);
    rowptr[1] = (int*)alloc((size_t)(NPAT + 1) * 4);
    rowptr[2] = (int*)alloc((size_t)(NNDC + 1) * 4);
    rowptr[3] = (int*)alloc((size_t)(NPAT + 1) * 4);
    int* deg    = (int*)alloc((size_t)NTOT * 4);
    int* cursor = (int*)alloc((size_t)NTOT * 4);
    int* part   = (int*)alloc((size_t)256 * 4);
    // prepped weights
    unsigned short* Wb0   = (unsigned short*)alloc((size_t)2 * 640 * 128 * 2);
    unsigned short* Wb1   = (unsigned short*)alloc((size_t)2 * 384 * 128 * 2);
    unsigned short* Wb2   = (unsigned short*)alloc((size_t)2 * 384 * 128 * 2);
    unsigned short* Wtaw  = (unsigned short*)alloc((size_t)6 * 128 * 128 * 2);
    unsigned short* Wtin  = (unsigned short*)alloc((size_t)128 * 128 * 2);
    unsigned short* Wtout = (unsigned short*)alloc((size_t)OUTN * 128 * 2);
    float* bb0 = (float*)alloc((size_t)2 * 640 * 4);
    float* bb1 = (float*)alloc((size_t)2 * 384 * 4);
    float* bb2 = (float*)alloc((size_t)2 * 384 * 4);
    unsigned int* esRel[4];
    for (int r = 0; r < 4; r++) esRel[r] = esbig + (size_t)r * NEDGE;

    auto gemm = [&](const void* A, int a_mode, int lda,
                    const unsigned short* Wt, const float* bias,
                    void* C, int c_mode, int ldc, int M, int N, int act,
                    const unsigned short* xold, int ldx,
                    const float* skipv, int skipidx) {
        dim3 grid((M + 63) / 64, (N + 63) / 64);
        gemm_mfma<<<grid, dim3(256), 0, stream>>>(A, a_mode, lda, Wt, bias,
            C, c_mode, ldc, M, N, act, xold, ldx, skipv, skipidx);
    };

    // ---- weight prep ----
    {
        wprep_kernel<<<dim3(4, 4, 2), 256, 0, stream>>>(qw, Wb0, 128, 128,
            (size_t)3 * 16384, (size_t)640 * 128, 0);
        wprep_kernel<<<dim3(4, 4, 2), 256, 0, stream>>>(qw + 16384, Wb1, 128, 128,
            (size_t)3 * 16384, (size_t)384 * 128, 0);
        wprep_kernel<<<dim3(4, 4, 2), 256, 0, stream>>>(qw + 2 * 16384, Wb2, 128, 128,
            (size_t)3 * 16384, (size_t)384 * 128, 0);
        wcomp_kernel<<<16, 256, 0, stream>>>(kw, vw, a_rel, m_rel, kbias, vbias,
            Wb0, Wb1, Wb2, bb0, bb1, bb2);
        biasq_kernel<<<3, 256, 0, stream>>>(qbias, bb0, bb1, bb2);
        wprep_kernel<<<dim3(4, 4, 6), 256, 0, stream>>>(aw, Wtaw, 128, 128,
            (size_t)128 * 128, (size_t)128 * 128, 0);
        wprep_kernel<<<dim3(4, 4, 1), 256, 0, stream>>>(w_in, Wtin, 128, 128, 0, 0, 0);
        wprep_kernel<<<dim3(4, 3, 1), 256, 0, stream>>>(w_out, Wtout, 128, OUTN, 0, 0, 0);
    }

    // ---- batched CSR build ----
    {
        const int NB = (NTOT + 1023) / 1024;
        hipMemsetAsync(deg, 0, (size_t)NTOT * 4, stream);
        hist4_kernel<<<dim3(64, 4), 256, 0, stream>>>(
            edst[0], edst[1], edst[2], edst[3], deg);
        scanA_kernel<<<NB, 256, 0, stream>>>(deg, part, NTOT);
        scanB_kernel<<<1, 128, 0, stream>>>(part, NB);
        scanC_kernel<<<NB, 256, 0, stream>>>(deg, part,
            rowptr[0], rowptr[1], rowptr[2], rowptr[3], cursor, NTOT);
        scatter_pack_kernel<<<dim3(64, 4), 256, 0, stream>>>(
            esrc[0], edst[0], esrc[1], edst[1], esrc[2], edst[2], esrc[3], edst[3],
            cursor, esbig);
    }

    // ---- input projections ----
    gemm(x_patient, 1, 128, Wtin, b_in, xb[0], 0, 128, NPAT, 128, 1, nullptr, 0, nullptr, 0);
    gather_relu_kernel<<<(NICD * CDIM + 255) / 256, 256, 0, stream>>>(emb_icd, x_icd, xb[1], NICD);
    gather_relu_kernel<<<(NNDC * CDIM + 255) / 256, 256, 0, stream>>>(emb_ndc, x_ndc, xb[2], NNDC);

    // ---- layers ----
    for (int l = 0; l < NLAYER; l++) {
        gemm(xb[0], 0, 128, Wb0 + (size_t)l * 640 * 128, bb0 + (size_t)l * 640,
             P0, 0, 640, NPAT, 640, 0, nullptr, 0, nullptr, 0);
        gemm(xb[1], 0, 128, Wb1 + (size_t)l * 384 * 128, bb1 + (size_t)l * 384,
             P1, 0, 384, NICD, 384, 0, nullptr, 0, nullptr, 0);
        gemm(xb[2], 0, 128, Wb2 + (size_t)l * 384 * 128, bb2 + (size_t)l * 384,
             P2, 0, 384, NNDC, 384, 0, nullptr, 0, nullptr, 0);
        hipMemsetAsync(agg[1], 0, (size_t)(NICD + NNDC) * CDIM * 4, stream);

        // r=0: patient -> icd
        edge_logits_kernel<<<(NEDGE * NHEAD + 255) / 256, 256, 0, stream>>>(
            esRel[0], P1, 384, P0 + 128, 640,
            p_rel + (size_t)(l * 4 + 0) * NHEAD, alphabuf);
        seg_stats_kernel<<<(NICD + 3) / 4, 256, 0, stream>>>(
            rowptr[0], alphabuf, statsbuf, NICD);
        seg_agg_kernel<<<(NEDGE + EPB - 1) / EPB, 128, 0, stream>>>(
            esRel[0], alphabuf, statsbuf, P0 + 256, 640, agg[1], NEDGE);

        // r=2: patient -> ndc
        edge_logits_kernel<<<(NEDGE * NHEAD + 255) / 256, 256, 0, stream>>>(
            esRel[2], P2, 384, P0 + 384, 640,
            p_rel + (size_t)(l * 4 + 2) * NHEAD, alphabuf);
        seg_stats_kernel<<<(NNDC + 3) / 4, 256, 0, stream>>>(
            rowptr[2], alphabuf, statsbuf, NNDC);
        seg_agg_kernel<<<(NEDGE + EPB - 1) / EPB, 128, 0, stream>>>(
            esRel[2], alphabuf, statsbuf, P0 + 512, 640, agg[2], NEDGE);

        // r=1 + r=3: paired waves (one per relation), pure store of agg[0]
        edge_softmax_agg2_kernel<<<(NPAT + 1) / 2, 256, 0, stream>>>(
            rowptr[1], esRel[1], rowptr[3], esRel[3],
            P0, 640, P1 + 128, P1 + 256, 384, P2 + 128, P2 + 256, 384,
            p_rel + (size_t)(l * 4 + 1) * NHEAD, p_rel + (size_t)(l * 4 + 3) * NHEAD,
            agg[0], NPAT);

        // gelu + skip output projections
        for (int t = 0; t < 3; t++) {
            int wi = l * 3 + t;
            gemm(agg[t], 2, 128, Wtaw + (size_t)wi * 128 * 128, abias + (size_t)wi * 128,
                 xb[t], 0, 128, sizes[t], 128, 0, xb[t], 128, skip, wi);
        }
    }

    // ---- output head (fp32 out) ----
    gemm(xb[0], 0, 128, Wtout, b_out, d_out, 1, OUTN, NPAT, OUTN, 2, nullptr, 0, nullptr, 0);
}